// Round 12
// baseline (501.104 us; speedup 1.0000x reference)
//
#include <hip/hip_runtime.h>
#include <hip/hip_bf16.h>
#include <stdint.h>

#define B_  32
#define L_  256
#define T_  32
#define D_  300
#define H_  256
#define G3  768   // 3*H

__device__ __forceinline__ int sdot4(uint32_t a, uint32_t b, int acc) {
#if defined(__has_builtin) && __has_builtin(__builtin_amdgcn_sdot4)
  return __builtin_amdgcn_sdot4((int)a, (int)b, acc, false);
#else
  const int a0 = (int)(signed char)(a & 0xff),  b0 = (int)(signed char)(b & 0xff);
  const int a1 = (int)(signed char)((a >> 8) & 0xff),  b1 = (int)(signed char)((b >> 8) & 0xff);
  const int a2 = (int)(signed char)((a >> 16) & 0xff), b2 = (int)(signed char)((b >> 16) & 0xff);
  const int a3 = (int)(signed char)(a >> 24),          b3 = (int)(signed char)(b >> 24);
  return acc + a0 * b0 + a1 * b1 + a2 * b2 + a3 * b3;
#endif
}

__device__ __forceinline__ float rcp_f(float x) { return __builtin_amdgcn_rcpf(x); }
__device__ __forceinline__ float sigmoid_f(float x) { return rcp_f(1.0f + __expf(-x)); }
__device__ __forceinline__ float tanh_f(float x) {
  float e2 = __expf(2.0f * x);
  return 1.0f - 2.0f * rcp_f(e2 + 1.0f);
}

// ---- pack Whh [768][256] f32 -> wQ i8 [64 kgroups][768 rows] + sw[768] ----
// sw premultiplied by 1/127 (h scale): a = idot * sw.
__global__ __launch_bounds__(256)
void pack_whh_i8(const float* __restrict__ Whh, uint32_t* __restrict__ wQ,
                 float* __restrict__ sw) {
  const int row = blockIdx.x * 4 + (threadIdx.x >> 6);
  const int lane = threadIdx.x & 63;
  const float* wr = Whh + (long)row * H_;
  float m = 0.0f;
#pragma unroll
  for (int u = 0; u < 4; ++u) m = fmaxf(m, fabsf(wr[lane + 64 * u]));
  for (int off = 32; off > 0; off >>= 1) m = fmaxf(m, __shfl_xor(m, off, 64));
  const float inv = m > 0.0f ? 127.0f / m : 0.0f;
  if (lane == 0) sw[row] = m > 0.0f ? m / (127.0f * 127.0f) : 0.0f;
  uint32_t d = 0;
#pragma unroll
  for (int u = 0; u < 4; ++u) {
    int qv = __float2int_rn(wr[4 * lane + u] * inv);
    qv = qv > 127 ? 127 : (qv < -127 ? -127 : qv);
    d |= ((uint32_t)(qv & 0xff)) << (8 * u);
  }
  wQ[lane * G3 + row] = d;
}

// ---- generic per-row symmetric i8 quantizer: out[row][kd] dwords + scale ----
// scale = rowmax/127 (dequant scale). rowidx gathers rows if non-null.
__global__ __launch_bounds__(256)
void quant_rows(const float* __restrict__ A, const int* __restrict__ rowidx,
                uint32_t* __restrict__ out, float* __restrict__ scale,
                int M, int K, int Kd) {
  const int row = blockIdx.x * 4 + (threadIdx.x >> 6);
  const int lane = threadIdx.x & 63;
  if (row >= M) return;
  const float* ar = A + (long)(rowidx ? rowidx[row] : row) * K;
  float m = 0.0f;
  for (int e = lane; e < K; e += 64) m = fmaxf(m, fabsf(ar[e]));
  for (int off = 32; off > 0; off >>= 1) m = fmaxf(m, __shfl_xor(m, off, 64));
  const float inv = m > 0.0f ? 127.0f / m : 0.0f;
  if (lane == 0) scale[row] = m * (1.0f / 127.0f);
  for (int kd = lane; kd < Kd; kd += 64) {
    uint32_t d = 0;
#pragma unroll
    for (int u = 0; u < 4; ++u) {
      const int e = 4 * kd + u;
      int qv = (e < K) ? __float2int_rn(ar[e] * inv) : 0;
      qv = qv > 127 ? 127 : (qv < -127 ? -127 : qv);
      d |= ((uint32_t)(qv & 0xff)) << (8 * u);
    }
    out[(long)row * Kd + kd] = d;
  }
}

// ---- bsum = bih + bhh for gates r,z; bih only for gate n ----
__global__ void bias_combine(const float* __restrict__ bih, const float* __restrict__ bhh,
                             float* __restrict__ bsum) {
  const int i = blockIdx.x * 256 + threadIdx.x;   // 0..767
  float v = bih[i];
  if (i < 2 * H_) v += bhh[i];
  bsum[i] = v;
}

// ---- dtok[i] = Xin[b*L + Xindex[i]] ----
__global__ void gather_dtok(const int* __restrict__ Xin, const int* __restrict__ Xindex,
                            int* __restrict__ dtok) {
  const int i = blockIdx.x * 256 + threadIdx.x;   // 0..1023
  const int b = i >> 5;                           // /T_
  dtok[i] = Xin[b * L_ + Xindex[i]];
}

// ---- i8 GEMM: C[M,N] = (Aq . Wq^T) * sa[m] * sw[n] (+bias[n]) ----
// 64x64 tile, 256 threads, 4x4 acc/thread, LDS staged kd-major for b128 reads.
template<bool TRANSP, bool BIAS>
__global__ __launch_bounds__(256)
void gemm_i8(const uint32_t* __restrict__ Aq, const float* __restrict__ sa,
             const uint32_t* __restrict__ Wq, const float* __restrict__ swc,
             const float* __restrict__ bias, float* __restrict__ C,
             int M, int N, int Kd) {
  __shared__ uint32_t As[8][68];
  __shared__ uint32_t Ws[8][68];
  const int tid = threadIdx.x;
  const int bm = blockIdx.x, bn = blockIdx.y;
  const int ty = tid >> 4, tx = tid & 15;
  const int srow = tid >> 2;
  const int skd = (tid & 3) << 1;
  const uint32_t* Arow = Aq + (long)(bm * 64 + srow) * Kd + skd;
  const uint32_t* Wrow = Wq + (long)(bn * 64 + srow) * Kd + skd;
  int acc[4][4] = {};
  for (int k0 = 0; k0 < Kd; k0 += 8) {
    const uint32_t a0 = Arow[k0], a1 = Arow[k0 + 1];
    const uint32_t w0 = Wrow[k0], w1 = Wrow[k0 + 1];
    __syncthreads();
    As[skd][srow] = a0; As[skd + 1][srow] = a1;
    Ws[skd][srow] = w0; Ws[skd + 1][srow] = w1;
    __syncthreads();
#pragma unroll
    for (int kd = 0; kd < 8; ++kd) {
      const uint4 a4 = *(const uint4*)&As[kd][ty << 2];
      const uint4 b4 = *(const uint4*)&Ws[kd][tx << 2];
      acc[0][0] = sdot4(a4.x, b4.x, acc[0][0]);
      acc[0][1] = sdot4(a4.x, b4.y, acc[0][1]);
      acc[0][2] = sdot4(a4.x, b4.z, acc[0][2]);
      acc[0][3] = sdot4(a4.x, b4.w, acc[0][3]);
      acc[1][0] = sdot4(a4.y, b4.x, acc[1][0]);
      acc[1][1] = sdot4(a4.y, b4.y, acc[1][1]);
      acc[1][2] = sdot4(a4.y, b4.z, acc[1][2]);
      acc[1][3] = sdot4(a4.y, b4.w, acc[1][3]);
      acc[2][0] = sdot4(a4.z, b4.x, acc[2][0]);
      acc[2][1] = sdot4(a4.z, b4.y, acc[2][1]);
      acc[2][2] = sdot4(a4.z, b4.z, acc[2][2]);
      acc[2][3] = sdot4(a4.z, b4.w, acc[2][3]);
      acc[3][0] = sdot4(a4.w, b4.x, acc[3][0]);
      acc[3][1] = sdot4(a4.w, b4.y, acc[3][1]);
      acc[3][2] = sdot4(a4.w, b4.z, acc[3][2]);
      acc[3][3] = sdot4(a4.w, b4.w, acc[3][3]);
    }
  }
#pragma unroll
  for (int i = 0; i < 4; ++i) {
    const int m = bm * 64 + (ty << 2) + i;
    const float sai = sa[m];
#pragma unroll
    for (int j = 0; j < 4; ++j) {
      const int n = bn * 64 + (tx << 2) + j;
      float v = (float)acc[i][j] * sai * swc[n];
      if (BIAS) v += bias[n];
      if (TRANSP) C[(((long)(m >> 8) * N + n) << 8) + (m & 255)] = v;
      else        C[(long)m * N + n] = v;
    }
  }
}

// ====== sequential GRU, 256 threads, weights in AGPRs (explicit stash) ======
// Thread j owns rows {j, H+j, 2H+j}, full K=256 = 192 i8-dwords, stashed in
// AGPRs via v_accvgpr_write (the "a" constraint bypasses the allocator's
// occupancy heuristic that refused >132 arch VGPRs for 10 rounds). Per step:
// 192 accvgpr_read + 192 sdot4 + 16 ds_read_b128. h as i8 in double-buffered
// LDS; 1 barrier/step; no cross-thread reduction.

__device__ __forceinline__ uint4 ld4q(const uint32_t* __restrict__ b, int row, int u) {
  uint4 v;
  v.x = b[(4 * u + 0) * G3 + row];
  v.y = b[(4 * u + 1) * G3 + row];
  v.z = b[(4 * u + 2) * G3 + row];
  v.w = b[(4 * u + 3) * G3 + row];
  return v;
}

#define AW(a_, v_) asm volatile("v_accvgpr_write_b32 %0, %1" : "=a"(a_) : "v"(v_))
#define AR(v_, a_) asm volatile("v_accvgpr_read_b32 %0, %1" : "=v"(v_) : "a"(a_))
#define AW4(d, s) AW(d.x, s.x); AW(d.y, s.y); AW(d.z, s.z); AW(d.w, s.w)

#define WDECL16(p) uint4 p##0, p##1, p##2, p##3, p##4, p##5, p##6, p##7, \
                         p##8, p##9, p##10, p##11, p##12, p##13, p##14, p##15
#define WLOAD16(p, base, row) \
  p##0  = ld4q(base, row, 0);  p##1  = ld4q(base, row, 1);  \
  p##2  = ld4q(base, row, 2);  p##3  = ld4q(base, row, 3);  \
  p##4  = ld4q(base, row, 4);  p##5  = ld4q(base, row, 5);  \
  p##6  = ld4q(base, row, 6);  p##7  = ld4q(base, row, 7);  \
  p##8  = ld4q(base, row, 8);  p##9  = ld4q(base, row, 9);  \
  p##10 = ld4q(base, row, 10); p##11 = ld4q(base, row, 11); \
  p##12 = ld4q(base, row, 12); p##13 = ld4q(base, row, 13); \
  p##14 = ld4q(base, row, 14); p##15 = ld4q(base, row, 15)
#define ASTASH16(p) \
  AW4(p##0, vt0);   AW4(p##1, vt1);   AW4(p##2, vt2);   AW4(p##3, vt3);   \
  AW4(p##4, vt4);   AW4(p##5, vt5);   AW4(p##6, vt6);   AW4(p##7, vt7);   \
  AW4(p##8, vt8);   AW4(p##9, vt9);   AW4(p##10, vt10); AW4(p##11, vt11); \
  AW4(p##12, vt12); AW4(p##13, vt13); AW4(p##14, vt14); AW4(p##15, vt15)

#define CHUNK(c) { \
  const uint4 hp = hq[c]; \
  uint32_t wv0, wv1, wv2, wv3; \
  AR(wv0, awr##c.x); AR(wv1, awr##c.y); AR(wv2, awr##c.z); AR(wv3, awr##c.w); \
  ar = sdot4(wv0, hp.x, ar); ar = sdot4(wv1, hp.y, ar); \
  ar = sdot4(wv2, hp.z, ar); ar = sdot4(wv3, hp.w, ar); \
  AR(wv0, awz##c.x); AR(wv1, awz##c.y); AR(wv2, awz##c.z); AR(wv3, awz##c.w); \
  az = sdot4(wv0, hp.x, az); az = sdot4(wv1, hp.y, az); \
  az = sdot4(wv2, hp.z, az); az = sdot4(wv3, hp.w, az); \
  AR(wv0, awn##c.x); AR(wv1, awn##c.y); AR(wv2, awn##c.z); AR(wv3, awn##c.w); \
  an = sdot4(wv0, hp.x, an); an = sdot4(wv1, hp.y, an); \
  an = sdot4(wv2, hp.z, an); an = sdot4(wv3, hp.w, an); }

__global__ __attribute__((amdgpu_flat_work_group_size(256, 256), amdgpu_waves_per_eu(1, 1)))
void gru_seq(const float* __restrict__ xg, const uint32_t* __restrict__ wQ,
             const float* __restrict__ sw, const float* __restrict__ bhh,
             const float* __restrict__ h0, float* __restrict__ hout,
             float* __restrict__ hlast, int S) {
  const int b = blockIdx.x;
  const int j = threadIdx.x;
  WDECL16(awr); WDECL16(awz); WDECL16(awn);
  {
    WDECL16(vt);
    WLOAD16(vt, wQ, j);          ASTASH16(awr);
    WLOAD16(vt, wQ, H_ + j);     ASTASH16(awz);
    WLOAD16(vt, wQ, 2 * H_ + j); ASTASH16(awn);
  }
  __shared__ __align__(16) uint32_t h2[2][H_ / 4];   // i8 h, double-buffered
  const float bhn = bhh[2 * H_ + j];
  const float swr = sw[j], swz = sw[H_ + j], swn = sw[2 * H_ + j];
  float h = h0 ? h0[b * H_ + j] : 0.0f;
  ((signed char*)h2[0])[j] = (signed char)__float2int_rn(h * 127.0f);
  const float* xp = xg + (long)b * S * G3;
  float* hp_out = hout + (long)b * S * H_;
  float xr = xp[j], xz = xp[H_ + j], xn = xp[2 * H_ + j];
  __syncthreads();
  for (int t = 0; t < S; ++t) {
    // prefetch next step's x under the dot chain
    float nxr = 0.0f, nxz = 0.0f, nxn = 0.0f;
    if (t + 1 < S) { nxr = xp[G3 + j]; nxz = xp[G3 + H_ + j]; nxn = xp[G3 + 2 * H_ + j]; }
    int ar = 0, az = 0, an = 0;
    const uint4* hq = (const uint4*)h2[t & 1];
    CHUNK(0)  CHUNK(1)  CHUNK(2)  CHUNK(3)
    CHUNK(4)  CHUNK(5)  CHUNK(6)  CHUNK(7)
    CHUNK(8)  CHUNK(9)  CHUNK(10) CHUNK(11)
    CHUNK(12) CHUNK(13) CHUNK(14) CHUNK(15)
    const float r = sigmoid_f(xr + (float)ar * swr);       // xr has bih_r+bhh_r
    const float z = sigmoid_f(xz + (float)az * swz);       // xz has bih_z+bhh_z
    const float n = tanh_f(xn + r * ((float)an * swn + bhn));
    h = (1.0f - z) * n + z * h;
    hp_out[j] = h;
    ((signed char*)h2[(t & 1) ^ 1])[j] = (signed char)__float2int_rn(h * 127.0f);
    xr = nxr; xz = nxz; xn = nxn;
    xp += G3;
    hp_out += H_;
    __syncthreads();
  }
  if (hlast) hlast[b * H_ + j] = h;
}

// ---- fused pointer layer + masked log-softmax + loss accumulation ----
__global__ __launch_bounds__(256)
void pointer_loss(const float* __restrict__ WEt, const float* __restrict__ WD,
                  const float* __restrict__ Vv,
                  const int* __restrict__ Xindex, const int* __restrict__ Yindex,
                  const int* __restrict__ lens, float* __restrict__ out) {
  const int t = blockIdx.x, b = blockIdx.y;
  const int l = threadIdx.x;
  __shared__ float wd_s[H_], vv_s[H_];
  __shared__ float rbuf[4], sbuf[4], vy_s;
  const int bt = b * T_ + t;
  wd_s[l] = WD[(long)bt * H_ + l];
  vv_s[l] = Vv[l] * 1.0507009873554805f;
  __syncthreads();
  const float* wet = WEt + (long)b * H_ * L_;
  const float alpha = 1.6732632423543772f;
  float acc = 0.0f;
#pragma unroll 4
  for (int hh = 0; hh < H_; ++hh) {
    const float xsum = wet[hh * L_ + l] + wd_s[hh];
    const float sneg = alpha * (__expf(xsum) - 1.0f);
    const float s = xsum > 0.0f ? xsum : sneg;
    acc = fmaf(s, vv_s[hh], acc);
  }
  float v;
  {
    const float sneg = alpha * (__expf(acc) - 1.0f);
    v = 1.0507009873554805f * (acc > 0.0f ? acc : sneg);
  }
  const int start = Xindex[bt];
  const int len = lens[b];
  const bool valid = (l >= start) && (l < len);
  const int y = Yindex[bt];
  if (l == y) vy_s = v;
  float m = valid ? v : -INFINITY;
  for (int off = 32; off > 0; off >>= 1) m = fmaxf(m, __shfl_xor(m, off, 64));
  const int wid = l >> 6, lane = l & 63;
  if (lane == 0) rbuf[wid] = m;
  __syncthreads();
  const float mx = fmaxf(fmaxf(rbuf[0], rbuf[1]), fmaxf(rbuf[2], rbuf[3]));
  float e = valid ? __expf(v - mx) : 0.0f;
  for (int off = 32; off > 0; off >>= 1) e += __shfl_xor(e, off, 64);
  if (lane == 0) sbuf[wid] = e;
  __syncthreads();
  if (l == 0) {
    const float sum = sbuf[0] + sbuf[1] + sbuf[2] + sbuf[3];
    atomicAdd(out, (mx + __logf(sum) - vy_s) * (1.0f / (B_ * T_)));
  }
}

extern "C" void kernel_launch(void* const* d_in, const int* in_sizes, int n_in,
                              void* d_out, int out_size, void* d_ws, size_t ws_size,
                              hipStream_t stream) {
  (void)in_sizes; (void)n_in; (void)out_size; (void)ws_size;
  const int*   Xin    = (const int*)d_in[0];
  const int*   Xindex = (const int*)d_in[1];
  const int*   Yindex = (const int*)d_in[2];
  const int*   lens   = (const int*)d_in[3];
  const float* emb    = (const float*)d_in[4];
  const float* Wih_e  = (const float*)d_in[5];
  const float* Whh_e  = (const float*)d_in[6];
  const float* bih_e  = (const float*)d_in[7];
  const float* bhh_e  = (const float*)d_in[8];
  const float* Wih_d  = (const float*)d_in[9];
  const float* Whh_d  = (const float*)d_in[10];
  const float* bih_d  = (const float*)d_in[11];
  const float* bhh_d  = (const float*)d_in[12];
  const float* W1     = (const float*)d_in[13];
  const float* W2     = (const float*)d_in[14];
  const float* Vv     = (const float*)d_in[15];

  char* p = (char*)d_ws;
  auto take = [&](size_t bytes) { void* q = (void*)p; p += (bytes + 255) & ~(size_t)255; return q; };
  uint32_t* wQ_e   = (uint32_t*)take((size_t)64 * G3 * 4);
  uint32_t* wQ_d   = (uint32_t*)take((size_t)64 * G3 * 4);
  float*    sw_e   = (float*)take((size_t)768 * 4);
  float*    sw_d   = (float*)take((size_t)768 * 4);
  uint32_t* WihQ_e = (uint32_t*)take((size_t)768 * 80 * 4);
  uint32_t* WihQ_d = (uint32_t*)take((size_t)768 * 80 * 4);
  float*    sWih_e = (float*)take((size_t)768 * 4);
  float*    sWih_d = (float*)take((size_t)768 * 4);
  uint32_t* W1q    = (uint32_t*)take((size_t)256 * 64 * 4);
  uint32_t* W2q    = (uint32_t*)take((size_t)256 * 64 * 4);
  float*    sW1    = (float*)take((size_t)256 * 4);
  float*    sW2    = (float*)take((size_t)256 * 4);
  float*    bsum_e = (float*)take((size_t)768 * 4);
  float*    bsum_d = (float*)take((size_t)768 * 4);
  int*      dtok   = (int*)take((size_t)1024 * 4);
  float*    xg_e   = (float*)take((size_t)8192 * 768 * 4);   // reused as WEt later
  float*    xg_d   = (float*)take((size_t)1024 * 768 * 4);
  float*    hn     = (float*)take((size_t)8192 * 256 * 4);
  float*    hend   = (float*)take((size_t)8192 * 4);
  float*    hl_d   = (float*)take((size_t)8192 * 4);
  float*    doutb  = (float*)take((size_t)1024 * 256 * 4);
  float*    WDb    = (float*)take((size_t)1024 * 256 * 4);
  uint32_t* Aqe    = (uint32_t*)take((size_t)8192 * 80 * 4); // reused as hnq later
  float*    saAe   = (float*)take((size_t)8192 * 4);         // reused as sahn
  uint32_t* Aqd    = (uint32_t*)take((size_t)1024 * 80 * 4); // reused as dq
  float*    saAd   = (float*)take((size_t)1024 * 4);         // reused as sad
  // aliases (regions dead by the time they're reused; stream is serial)
  float*    WEt  = xg_e;            // xg_e dead after encoder GRU
  uint32_t* hnq  = Aqe;             // Aqe dead after xg GEMMs
  float*    sahn = saAe;
  uint32_t* dq   = Aqd;
  float*    sad  = saAd;

  hipMemsetAsync(d_out, 0, sizeof(float), stream);

  hipLaunchKernelGGL(pack_whh_i8, dim3(192), dim3(256), 0, stream, Whh_e, wQ_e, sw_e);
  hipLaunchKernelGGL(pack_whh_i8, dim3(192), dim3(256), 0, stream, Whh_d, wQ_d, sw_d);
  hipLaunchKernelGGL(bias_combine, dim3(3), dim3(256), 0, stream, bih_e, bhh_e, bsum_e);
  hipLaunchKernelGGL(bias_combine, dim3(3), dim3(256), 0, stream, bih_d, bhh_d, bsum_d);
  hipLaunchKernelGGL(gather_dtok, dim3(4), dim3(256), 0, stream, Xin, Xindex, dtok);

  // quantize weights (per-row i8): Wih K=300->Kd=80, W1/W2 K=256->Kd=64
  hipLaunchKernelGGL(quant_rows, dim3(192), dim3(256), 0, stream,
                     Wih_e, (const int*)nullptr, WihQ_e, sWih_e, 768, 300, 80);
  hipLaunchKernelGGL(quant_rows, dim3(192), dim3(256), 0, stream,
                     Wih_d, (const int*)nullptr, WihQ_d, sWih_d, 768, 300, 80);
  hipLaunchKernelGGL(quant_rows, dim3(64), dim3(256), 0, stream,
                     W1, (const int*)nullptr, W1q, sW1, 256, 256, 64);
  hipLaunchKernelGGL(quant_rows, dim3(64), dim3(256), 0, stream,
                     W2, (const int*)nullptr, W2q, sW2, 256, 256, 64);
  // quantize gathered embedding rows
  hipLaunchKernelGGL(quant_rows, dim3(2048), dim3(256), 0, stream,
                     emb, Xin, Aqe, saAe, 8192, 300, 80);
  hipLaunchKernelGGL(quant_rows, dim3(256), dim3(256), 0, stream,
                     emb, dtok, Aqd, saAd, 1024, 300, 80);

  // xg = Aq @ WihQ^T scaled + bsum
  hipLaunchKernelGGL((gemm_i8<false, true>), dim3(128, 12), dim3(256), 0, stream,
                     Aqe, saAe, WihQ_e, sWih_e, bsum_e, xg_e, 8192, 768, 80);
  hipLaunchKernelGGL((gemm_i8<false, true>), dim3(16, 12), dim3(256), 0, stream,
                     Aqd, saAd, WihQ_d, sWih_d, bsum_d, xg_d, 1024, 768, 80);

  // encoder GRU (h0 = 0) -> hn, hend; decoder GRU (h0 = hend) -> doutb
  hipLaunchKernelGGL(gru_seq, dim3(32), dim3(256), 0, stream,
                     xg_e, wQ_e, sw_e, bhh_e, (const float*)nullptr, hn, hend, L_);
  hipLaunchKernelGGL(gru_seq, dim3(32), dim3(256), 0, stream,
                     xg_d, wQ_d, sw_d, bhh_d, hend, doutb, hl_d, T_);

  // quantize GRU outputs, then pointer GEMMs
  hipLaunchKernelGGL(quant_rows, dim3(2048), dim3(256), 0, stream,
                     hn, (const int*)nullptr, hnq, sahn, 8192, 256, 64);
  hipLaunchKernelGGL(quant_rows, dim3(256), dim3(256), 0, stream,
                     doutb, (const int*)nullptr, dq, sad, 1024, 256, 64);
  // WEt[b][k][l] (transposed store), WD[b,t,k]
  hipLaunchKernelGGL((gemm_i8<true, false>), dim3(128, 4), dim3(256), 0, stream,
                     hnq, sahn, W1q, sW1, (const float*)nullptr, WEt, 8192, 256, 64);
  hipLaunchKernelGGL((gemm_i8<false, false>), dim3(16, 4), dim3(256), 0, stream,
                     dq, sad, W2q, sW2, (const float*)nullptr, WDb, 1024, 256, 64);

  // fused pointer layer + loss
  hipLaunchKernelGGL(pointer_loss, dim3(T_, B_), dim3(256), 0, stream,
                     WEt, WDb, Vv, Xindex, Yindex, lens, (float*)d_out);
}

// Round 13
// 375.779 us; speedup vs baseline: 1.3335x; 1.3335x over previous
//
#include <hip/hip_runtime.h>
#include <hip/hip_bf16.h>
#include <stdint.h>

#define B_  32
#define L_  256
#define T_  32
#define D_  300
#define H_  256
#define G3  768   // 3*H

__device__ __forceinline__ int sdot4(uint32_t a, uint32_t b, int acc) {
#if defined(__has_builtin) && __has_builtin(__builtin_amdgcn_sdot4)
  return __builtin_amdgcn_sdot4((int)a, (int)b, acc, false);
#else
  const int a0 = (int)(signed char)(a & 0xff),  b0 = (int)(signed char)(b & 0xff);
  const int a1 = (int)(signed char)((a >> 8) & 0xff),  b1 = (int)(signed char)((b >> 8) & 0xff);
  const int a2 = (int)(signed char)((a >> 16) & 0xff), b2 = (int)(signed char)((b >> 16) & 0xff);
  const int a3 = (int)(signed char)(a >> 24),          b3 = (int)(signed char)(b >> 24);
  return acc + a0 * b0 + a1 * b1 + a2 * b2 + a3 * b3;
#endif
}

__device__ __forceinline__ float rcp_f(float x) { return __builtin_amdgcn_rcpf(x); }
__device__ __forceinline__ float sigmoid_f(float x) { return rcp_f(1.0f + __expf(-x)); }
__device__ __forceinline__ float tanh_f(float x) {
  float e2 = __expf(2.0f * x);
  return 1.0f - 2.0f * rcp_f(e2 + 1.0f);
}

// ---- pack Whh [768][256] f32 -> wQ i8 [64 kgroups][768 rows] + sw[768] ----
// sw premultiplied by 1/127 (h scale): a = idot * sw.
__global__ __launch_bounds__(256)
void pack_whh_i8(const float* __restrict__ Whh, uint32_t* __restrict__ wQ,
                 float* __restrict__ sw) {
  const int row = blockIdx.x * 4 + (threadIdx.x >> 6);
  const int lane = threadIdx.x & 63;
  const float* wr = Whh + (long)row * H_;
  float m = 0.0f;
#pragma unroll
  for (int u = 0; u < 4; ++u) m = fmaxf(m, fabsf(wr[lane + 64 * u]));
  for (int off = 32; off > 0; off >>= 1) m = fmaxf(m, __shfl_xor(m, off, 64));
  const float inv = m > 0.0f ? 127.0f / m : 0.0f;
  if (lane == 0) sw[row] = m > 0.0f ? m / (127.0f * 127.0f) : 0.0f;
  uint32_t d = 0;
#pragma unroll
  for (int u = 0; u < 4; ++u) {
    int qv = __float2int_rn(wr[4 * lane + u] * inv);
    qv = qv > 127 ? 127 : (qv < -127 ? -127 : qv);
    d |= ((uint32_t)(qv & 0xff)) << (8 * u);
  }
  wQ[lane * G3 + row] = d;
}

// ---- generic per-row symmetric i8 quantizer: out[row][kd] dwords + scale ----
__global__ __launch_bounds__(256)
void quant_rows(const float* __restrict__ A, const int* __restrict__ rowidx,
                uint32_t* __restrict__ out, float* __restrict__ scale,
                int M, int K, int Kd) {
  const int row = blockIdx.x * 4 + (threadIdx.x >> 6);
  const int lane = threadIdx.x & 63;
  if (row >= M) return;
  const float* ar = A + (long)(rowidx ? rowidx[row] : row) * K;
  float m = 0.0f;
  for (int e = lane; e < K; e += 64) m = fmaxf(m, fabsf(ar[e]));
  for (int off = 32; off > 0; off >>= 1) m = fmaxf(m, __shfl_xor(m, off, 64));
  const float inv = m > 0.0f ? 127.0f / m : 0.0f;
  if (lane == 0) scale[row] = m * (1.0f / 127.0f);
  for (int kd = lane; kd < Kd; kd += 64) {
    uint32_t d = 0;
#pragma unroll
    for (int u = 0; u < 4; ++u) {
      const int e = 4 * kd + u;
      int qv = (e < K) ? __float2int_rn(ar[e] * inv) : 0;
      qv = qv > 127 ? 127 : (qv < -127 ? -127 : qv);
      d |= ((uint32_t)(qv & 0xff)) << (8 * u);
    }
    out[(long)row * Kd + kd] = d;
  }
}

// ---- bsum = bih + bhh for gates r,z; bih only for gate n ----
__global__ void bias_combine(const float* __restrict__ bih, const float* __restrict__ bhh,
                             float* __restrict__ bsum) {
  const int i = blockIdx.x * 256 + threadIdx.x;   // 0..767
  float v = bih[i];
  if (i < 2 * H_) v += bhh[i];
  bsum[i] = v;
}

// ---- dtok[i] = Xin[b*L + Xindex[i]] ----
__global__ void gather_dtok(const int* __restrict__ Xin, const int* __restrict__ Xindex,
                            int* __restrict__ dtok) {
  const int i = blockIdx.x * 256 + threadIdx.x;   // 0..1023
  const int b = i >> 5;                           // /T_
  dtok[i] = Xin[b * L_ + Xindex[i]];
}

// ---- i8 GEMM: C[M,N] = (Aq . Wq^T) * sa[m] * sw[n] (+bias[n]) ----
template<bool TRANSP, bool BIAS>
__global__ __launch_bounds__(256)
void gemm_i8(const uint32_t* __restrict__ Aq, const float* __restrict__ sa,
             const uint32_t* __restrict__ Wq, const float* __restrict__ swc,
             const float* __restrict__ bias, float* __restrict__ C,
             int M, int N, int Kd) {
  __shared__ uint32_t As[8][68];
  __shared__ uint32_t Ws[8][68];
  const int tid = threadIdx.x;
  const int bm = blockIdx.x, bn = blockIdx.y;
  const int ty = tid >> 4, tx = tid & 15;
  const int srow = tid >> 2;
  const int skd = (tid & 3) << 1;
  const uint32_t* Arow = Aq + (long)(bm * 64 + srow) * Kd + skd;
  const uint32_t* Wrow = Wq + (long)(bn * 64 + srow) * Kd + skd;
  int acc[4][4] = {};
  for (int k0 = 0; k0 < Kd; k0 += 8) {
    const uint32_t a0 = Arow[k0], a1 = Arow[k0 + 1];
    const uint32_t w0 = Wrow[k0], w1 = Wrow[k0 + 1];
    __syncthreads();
    As[skd][srow] = a0; As[skd + 1][srow] = a1;
    Ws[skd][srow] = w0; Ws[skd + 1][srow] = w1;
    __syncthreads();
#pragma unroll
    for (int kd = 0; kd < 8; ++kd) {
      const uint4 a4 = *(const uint4*)&As[kd][ty << 2];
      const uint4 b4 = *(const uint4*)&Ws[kd][tx << 2];
      acc[0][0] = sdot4(a4.x, b4.x, acc[0][0]);
      acc[0][1] = sdot4(a4.x, b4.y, acc[0][1]);
      acc[0][2] = sdot4(a4.x, b4.z, acc[0][2]);
      acc[0][3] = sdot4(a4.x, b4.w, acc[0][3]);
      acc[1][0] = sdot4(a4.y, b4.x, acc[1][0]);
      acc[1][1] = sdot4(a4.y, b4.y, acc[1][1]);
      acc[1][2] = sdot4(a4.y, b4.z, acc[1][2]);
      acc[1][3] = sdot4(a4.y, b4.w, acc[1][3]);
      acc[2][0] = sdot4(a4.z, b4.x, acc[2][0]);
      acc[2][1] = sdot4(a4.z, b4.y, acc[2][1]);
      acc[2][2] = sdot4(a4.z, b4.z, acc[2][2]);
      acc[2][3] = sdot4(a4.z, b4.w, acc[2][3]);
      acc[3][0] = sdot4(a4.w, b4.x, acc[3][0]);
      acc[3][1] = sdot4(a4.w, b4.y, acc[3][1]);
      acc[3][2] = sdot4(a4.w, b4.z, acc[3][2]);
      acc[3][3] = sdot4(a4.w, b4.w, acc[3][3]);
    }
  }
#pragma unroll
  for (int i = 0; i < 4; ++i) {
    const int m = bm * 64 + (ty << 2) + i;
    const float sai = sa[m];
#pragma unroll
    for (int j = 0; j < 4; ++j) {
      const int n = bn * 64 + (tx << 2) + j;
      float v = (float)acc[i][j] * sai * swc[n];
      if (BIAS) v += bias[n];
      if (TRANSP) C[(((long)(m >> 8) * N + n) << 8) + (m & 255)] = v;
      else        C[(long)m * N + n] = v;
    }
  }
}

// ==== sequential GRU, 1024 threads, 4-way K-split, weights LDS+registers ====
// tid = q*256+j; thread owns rows {j,H+j,2H+j}, k-dwords [q*16, q*16+16) =
// 12 uint4. Placement: 6 uint4 in LDS (96 KB, staged once, stride-16B
// conflict-free b128 reads) + 6 uint4 pinned in registers (24 VGPR, fits the
// ~64 grant at 1024 thr). ZERO in-loop global weight traffic -> the per-CU
// L2 port (r8's 1650 cy/step bound) is off the critical path; LDS pipe
// (~770 cy) and VALU (~400 cy) run concurrently.

__device__ __forceinline__ uint4 ld4q(const uint32_t* __restrict__ b, int row, int u) {
  uint4 v;
  v.x = b[(4 * u + 0) * G3 + row];
  v.y = b[(4 * u + 1) * G3 + row];
  v.z = b[(4 * u + 2) * G3 + row];
  v.w = b[(4 * u + 3) * G3 + row];
  return v;
}

#define PIN4(v) asm volatile("" : "+v"(v.x), "+v"(v.y), "+v"(v.z), "+v"(v.w))
#define DOT4W(accv, wv, hp) { \
  accv = sdot4(wv.x, hp.x, accv); accv = sdot4(wv.y, hp.y, accv); \
  accv = sdot4(wv.z, hp.z, accv); accv = sdot4(wv.w, hp.w, accv); }

__global__ __launch_bounds__(1024)
void gru_seq(const float* __restrict__ xg, const uint32_t* __restrict__ wQ,
             const float* __restrict__ sw, const float* __restrict__ bhh,
             const float* __restrict__ h0, float* __restrict__ hout,
             float* __restrict__ hlast, int S) {
  const int b = blockIdx.x;
  const int tid = threadIdx.x;
  const int j = tid & 255;
  const int q = tid >> 8;
  const uint32_t* wbase = wQ + (size_t)q * 16 * G3;   // k-dword base = q*16
  __shared__ uint4 wL[6][1024];                       // 96 KB weight cache
  __shared__ __align__(16) uint32_t h2[2][H_ / 4];    // i8 h, double-buffered
  __shared__ int part[3][4][H_];                      // [gate][q][j]; q=0 unused
  // stage chunks u=0,1 of each gate row into LDS
  wL[0][tid] = ld4q(wbase, j, 0);
  wL[1][tid] = ld4q(wbase, j, 1);
  wL[2][tid] = ld4q(wbase, H_ + j, 0);
  wL[3][tid] = ld4q(wbase, H_ + j, 1);
  wL[4][tid] = ld4q(wbase, 2 * H_ + j, 0);
  wL[5][tid] = ld4q(wbase, 2 * H_ + j, 1);
  // chunks u=2,3 live in registers
  uint4 wr2 = ld4q(wbase, j, 2),          wr3 = ld4q(wbase, j, 3);
  uint4 wz2 = ld4q(wbase, H_ + j, 2),     wz3 = ld4q(wbase, H_ + j, 3);
  uint4 wn2 = ld4q(wbase, 2 * H_ + j, 2), wn3 = ld4q(wbase, 2 * H_ + j, 3);
  PIN4(wr2); PIN4(wr3); PIN4(wz2); PIN4(wz3); PIN4(wn2); PIN4(wn3);
  float bhn = 0.0f, h = 0.0f, swr = 0.0f, swz = 0.0f, swn = 0.0f;
  const float* xp = xg + (long)b * S * G3;
  float* hp_out = hout + (long)b * S * H_;
  if (q == 0) {
    bhn = bhh[2 * H_ + j];
    swr = sw[j]; swz = sw[H_ + j]; swn = sw[2 * H_ + j];
    h = h0 ? h0[b * H_ + j] : 0.0f;
    ((signed char*)h2[0])[j] = (signed char)__float2int_rn(h * 127.0f);
  }
  __syncthreads();
  const uint4* wlb = &wL[0][tid];
  for (int t = 0; t < S; ++t) {
    float xr = 0.0f, xz = 0.0f, xn = 0.0f;
    if (q == 0) { xr = xp[j]; xz = xp[H_ + j]; xn = xp[2 * H_ + j]; }
    int ar = 0, az = 0, an = 0;
    const uint4* hq = (const uint4*)h2[t & 1] + q * 4;
    {
      const uint4 hp0 = hq[0], hp1 = hq[1];
      uint4 wv;
      wv = wlb[0];        DOT4W(ar, wv, hp0)
      wv = wlb[1024];     DOT4W(ar, wv, hp1)
      wv = wlb[2048];     DOT4W(az, wv, hp0)
      wv = wlb[3072];     DOT4W(az, wv, hp1)
      wv = wlb[4096];     DOT4W(an, wv, hp0)
      wv = wlb[5120];     DOT4W(an, wv, hp1)
    }
    __builtin_amdgcn_sched_barrier(0);
    {
      const uint4 hp2 = hq[2], hp3 = hq[3];
      DOT4W(ar, wr2, hp2)  DOT4W(ar, wr3, hp3)
      DOT4W(az, wz2, hp2)  DOT4W(az, wz3, hp3)
      DOT4W(an, wn2, hp2)  DOT4W(an, wn3, hp3)
    }
    if (q) { part[0][q][j] = ar; part[1][q][j] = az; part[2][q][j] = an; }
    __syncthreads();
    if (q == 0) {
      const float arf = (float)(ar + part[0][1][j] + part[0][2][j] + part[0][3][j]) * swr;
      const float azf = (float)(az + part[1][1][j] + part[1][2][j] + part[1][3][j]) * swz;
      const float anf = (float)(an + part[2][1][j] + part[2][2][j] + part[2][3][j]) * swn;
      const float r = sigmoid_f(xr + arf);           // xr has bih_r + bhh_r
      const float z = sigmoid_f(xz + azf);           // xz has bih_z + bhh_z
      const float n = tanh_f(xn + r * (anf + bhn));
      h = (1.0f - z) * n + z * h;
      hp_out[j] = h;
      ((signed char*)h2[(t & 1) ^ 1])[j] = (signed char)__float2int_rn(h * 127.0f);
    }
    xp += G3;
    hp_out += H_;
    __syncthreads();
  }
  if (q == 0 && hlast) hlast[b * H_ + j] = h;
}

// ---- fused pointer layer + masked log-softmax + loss accumulation ----
__global__ __launch_bounds__(256)
void pointer_loss(const float* __restrict__ WEt, const float* __restrict__ WD,
                  const float* __restrict__ Vv,
                  const int* __restrict__ Xindex, const int* __restrict__ Yindex,
                  const int* __restrict__ lens, float* __restrict__ out) {
  const int t = blockIdx.x, b = blockIdx.y;
  const int l = threadIdx.x;
  __shared__ float wd_s[H_], vv_s[H_];
  __shared__ float rbuf[4], sbuf[4], vy_s;
  const int bt = b * T_ + t;
  wd_s[l] = WD[(long)bt * H_ + l];
  vv_s[l] = Vv[l] * 1.0507009873554805f;
  __syncthreads();
  const float* wet = WEt + (long)b * H_ * L_;
  const float alpha = 1.6732632423543772f;
  float acc = 0.0f;
#pragma unroll 4
  for (int hh = 0; hh < H_; ++hh) {
    const float xsum = wet[hh * L_ + l] + wd_s[hh];
    const float sneg = alpha * (__expf(xsum) - 1.0f);
    const float s = xsum > 0.0f ? xsum : sneg;
    acc = fmaf(s, vv_s[hh], acc);
  }
  float v;
  {
    const float sneg = alpha * (__expf(acc) - 1.0f);
    v = 1.0507009873554805f * (acc > 0.0f ? acc : sneg);
  }
  const int start = Xindex[bt];
  const int len = lens[b];
  const bool valid = (l >= start) && (l < len);
  const int y = Yindex[bt];
  if (l == y) vy_s = v;
  float m = valid ? v : -INFINITY;
  for (int off = 32; off > 0; off >>= 1) m = fmaxf(m, __shfl_xor(m, off, 64));
  const int wid = l >> 6, lane = l & 63;
  if (lane == 0) rbuf[wid] = m;
  __syncthreads();
  const float mx = fmaxf(fmaxf(rbuf[0], rbuf[1]), fmaxf(rbuf[2], rbuf[3]));
  float e = valid ? __expf(v - mx) : 0.0f;
  for (int off = 32; off > 0; off >>= 1) e += __shfl_xor(e, off, 64);
  if (lane == 0) sbuf[wid] = e;
  __syncthreads();
  if (l == 0) {
    const float sum = sbuf[0] + sbuf[1] + sbuf[2] + sbuf[3];
    atomicAdd(out, (mx + __logf(sum) - vy_s) * (1.0f / (B_ * T_)));
  }
}

extern "C" void kernel_launch(void* const* d_in, const int* in_sizes, int n_in,
                              void* d_out, int out_size, void* d_ws, size_t ws_size,
                              hipStream_t stream) {
  (void)in_sizes; (void)n_in; (void)out_size; (void)ws_size;
  const int*   Xin    = (const int*)d_in[0];
  const int*   Xindex = (const int*)d_in[1];
  const int*   Yindex = (const int*)d_in[2];
  const int*   lens   = (const int*)d_in[3];
  const float* emb    = (const float*)d_in[4];
  const float* Wih_e  = (const float*)d_in[5];
  const float* Whh_e  = (const float*)d_in[6];
  const float* bih_e  = (const float*)d_in[7];
  const float* bhh_e  = (const float*)d_in[8];
  const float* Wih_d  = (const float*)d_in[9];
  const float* Whh_d  = (const float*)d_in[10];
  const float* bih_d  = (const float*)d_in[11];
  const float* bhh_d  = (const float*)d_in[12];
  const float* W1     = (const float*)d_in[13];
  const float* W2     = (const float*)d_in[14];
  const float* Vv     = (const float*)d_in[15];

  char* p = (char*)d_ws;
  auto take = [&](size_t bytes) { void* q = (void*)p; p += (bytes + 255) & ~(size_t)255; return q; };
  uint32_t* wQ_e   = (uint32_t*)take((size_t)64 * G3 * 4);
  uint32_t* wQ_d   = (uint32_t*)take((size_t)64 * G3 * 4);
  float*    sw_e   = (float*)take((size_t)768 * 4);
  float*    sw_d   = (float*)take((size_t)768 * 4);
  uint32_t* WihQ_e = (uint32_t*)take((size_t)768 * 80 * 4);
  uint32_t* WihQ_d = (uint32_t*)take((size_t)768 * 80 * 4);
  float*    sWih_e = (float*)take((size_t)768 * 4);
  float*    sWih_d = (float*)take((size_t)768 * 4);
  uint32_t* W1q    = (uint32_t*)take((size_t)256 * 64 * 4);
  uint32_t* W2q    = (uint32_t*)take((size_t)256 * 64 * 4);
  float*    sW1    = (float*)take((size_t)256 * 4);
  float*    sW2    = (float*)take((size_t)256 * 4);
  float*    bsum_e = (float*)take((size_t)768 * 4);
  float*    bsum_d = (float*)take((size_t)768 * 4);
  int*      dtok   = (int*)take((size_t)1024 * 4);
  float*    xg_e   = (float*)take((size_t)8192 * 768 * 4);   // reused as WEt later
  float*    xg_d   = (float*)take((size_t)1024 * 768 * 4);
  float*    hn     = (float*)take((size_t)8192 * 256 * 4);
  float*    hend   = (float*)take((size_t)8192 * 4);
  float*    hl_d   = (float*)take((size_t)8192 * 4);
  float*    doutb  = (float*)take((size_t)1024 * 256 * 4);
  float*    WDb    = (float*)take((size_t)1024 * 256 * 4);
  uint32_t* Aqe    = (uint32_t*)take((size_t)8192 * 80 * 4); // reused as hnq later
  float*    saAe   = (float*)take((size_t)8192 * 4);         // reused as sahn
  uint32_t* Aqd    = (uint32_t*)take((size_t)1024 * 80 * 4); // reused as dq
  float*    saAd   = (float*)take((size_t)1024 * 4);         // reused as sad
  float*    WEt  = xg_e;            // xg_e dead after encoder GRU
  uint32_t* hnq  = Aqe;             // Aqe dead after xg GEMMs
  float*    sahn = saAe;
  uint32_t* dq   = Aqd;
  float*    sad  = saAd;

  hipMemsetAsync(d_out, 0, sizeof(float), stream);

  hipLaunchKernelGGL(pack_whh_i8, dim3(192), dim3(256), 0, stream, Whh_e, wQ_e, sw_e);
  hipLaunchKernelGGL(pack_whh_i8, dim3(192), dim3(256), 0, stream, Whh_d, wQ_d, sw_d);
  hipLaunchKernelGGL(bias_combine, dim3(3), dim3(256), 0, stream, bih_e, bhh_e, bsum_e);
  hipLaunchKernelGGL(bias_combine, dim3(3), dim3(256), 0, stream, bih_d, bhh_d, bsum_d);
  hipLaunchKernelGGL(gather_dtok, dim3(4), dim3(256), 0, stream, Xin, Xindex, dtok);

  // quantize weights: Wih K=300->Kd=80, W1/W2 K=256->Kd=64
  hipLaunchKernelGGL(quant_rows, dim3(192), dim3(256), 0, stream,
                     Wih_e, (const int*)nullptr, WihQ_e, sWih_e, 768, 300, 80);
  hipLaunchKernelGGL(quant_rows, dim3(192), dim3(256), 0, stream,
                     Wih_d, (const int*)nullptr, WihQ_d, sWih_d, 768, 300, 80);
  hipLaunchKernelGGL(quant_rows, dim3(64), dim3(256), 0, stream,
                     W1, (const int*)nullptr, W1q, sW1, 256, 256, 64);
  hipLaunchKernelGGL(quant_rows, dim3(64), dim3(256), 0, stream,
                     W2, (const int*)nullptr, W2q, sW2, 256, 256, 64);
  // quantize gathered embedding rows
  hipLaunchKernelGGL(quant_rows, dim3(2048), dim3(256), 0, stream,
                     emb, Xin, Aqe, saAe, 8192, 300, 80);
  hipLaunchKernelGGL(quant_rows, dim3(256), dim3(256), 0, stream,
                     emb, dtok, Aqd, saAd, 1024, 300, 80);

  // xg = Aq @ WihQ^T scaled + bsum
  hipLaunchKernelGGL((gemm_i8<false, true>), dim3(128, 12), dim3(256), 0, stream,
                     Aqe, saAe, WihQ_e, sWih_e, bsum_e, xg_e, 8192, 768, 80);
  hipLaunchKernelGGL((gemm_i8<false, true>), dim3(16, 12), dim3(256), 0, stream,
                     Aqd, saAd, WihQ_d, sWih_d, bsum_d, xg_d, 1024, 768, 80);

  // encoder GRU (h0 = 0) -> hn, hend; decoder GRU (h0 = hend) -> doutb
  hipLaunchKernelGGL(gru_seq, dim3(32), dim3(1024), 0, stream,
                     xg_e, wQ_e, sw_e, bhh_e, (const float*)nullptr, hn, hend, L_);
  hipLaunchKernelGGL(gru_seq, dim3(32), dim3(1024), 0, stream,
                     xg_d, wQ_d, sw_d, bhh_d, hend, doutb, hl_d, T_);

  // quantize GRU outputs, then pointer GEMMs
  hipLaunchKernelGGL(quant_rows, dim3(2048), dim3(256), 0, stream,
                     hn, (const int*)nullptr, hnq, sahn, 8192, 256, 64);
  hipLaunchKernelGGL(quant_rows, dim3(256), dim3(256), 0, stream,
                     doutb, (const int*)nullptr, dq, sad, 1024, 256, 64);
  // WEt[b][k][l] (transposed store), WD[b,t,k]
  hipLaunchKernelGGL((gemm_i8<true, false>), dim3(128, 4), dim3(256), 0, stream,
                     hnq, sahn, W1q, sW1, (const float*)nullptr, WEt, 8192, 256, 64);
  hipLaunchKernelGGL((gemm_i8<false, false>), dim3(16, 4), dim3(256), 0, stream,
                     dq, sad, W2q, sW2, (const float*)nullptr, WDb, 1024, 256, 64);

  // fused pointer layer + loss
  hipLaunchKernelGGL(pointer_loss, dim3(T_, B_), dim3(256), 0, stream,
                     WEt, WDb, Vv, Xindex, Yindex, lens, (float*)d_out);
}

// Round 14
// 342.523 us; speedup vs baseline: 1.4630x; 1.0971x over previous
//
#include <hip/hip_runtime.h>
#include <hip/hip_bf16.h>
#include <stdint.h>

#define B_  32
#define L_  256
#define T_  32
#define D_  300
#define H_  256
#define G3  768   // 3*H

__device__ __forceinline__ int sdot4(uint32_t a, uint32_t b, int acc) {
#if defined(__has_builtin) && __has_builtin(__builtin_amdgcn_sdot4)
  return __builtin_amdgcn_sdot4((int)a, (int)b, acc, false);
#else
  const int a0 = (int)(signed char)(a & 0xff),  b0 = (int)(signed char)(b & 0xff);
  const int a1 = (int)(signed char)((a >> 8) & 0xff),  b1 = (int)(signed char)((b >> 8) & 0xff);
  const int a2 = (int)(signed char)((a >> 16) & 0xff), b2 = (int)(signed char)((b >> 16) & 0xff);
  const int a3 = (int)(signed char)(a >> 24),          b3 = (int)(signed char)(b >> 24);
  return acc + a0 * b0 + a1 * b1 + a2 * b2 + a3 * b3;
#endif
}

__device__ __forceinline__ float rcp_f(float x) { return __builtin_amdgcn_rcpf(x); }
__device__ __forceinline__ float sigmoid_f(float x) { return rcp_f(1.0f + __expf(-x)); }
__device__ __forceinline__ float tanh_f(float x) {
  float e2 = __expf(2.0f * x);
  return 1.0f - 2.0f * rcp_f(e2 + 1.0f);
}

// ---- pack Whh [768][256] f32 -> wQv uint4[16 chunks][768 rows] + sw[768] ----
// chunk c of row r (uint4 at index c*768+r) holds K-dwords 4c..4c+3 -> lanes
// with consecutive r stream coalesced dwordx4. sw premult by 1/127 (h scale).
__global__ __launch_bounds__(256)
void pack_whh_i8(const float* __restrict__ Whh, uint32_t* __restrict__ wQ,
                 float* __restrict__ sw) {
  const int row = blockIdx.x * 4 + (threadIdx.x >> 6);
  const int lane = threadIdx.x & 63;           // dword index 0..63
  const float* wr = Whh + (long)row * H_;
  float m = 0.0f;
#pragma unroll
  for (int u = 0; u < 4; ++u) m = fmaxf(m, fabsf(wr[lane + 64 * u]));
  for (int off = 32; off > 0; off >>= 1) m = fmaxf(m, __shfl_xor(m, off, 64));
  const float inv = m > 0.0f ? 127.0f / m : 0.0f;
  if (lane == 0) sw[row] = m > 0.0f ? m / (127.0f * 127.0f) : 0.0f;
  uint32_t d = 0;
#pragma unroll
  for (int u = 0; u < 4; ++u) {
    int qv = __float2int_rn(wr[4 * lane + u] * inv);
    qv = qv > 127 ? 127 : (qv < -127 ? -127 : qv);
    d |= ((uint32_t)(qv & 0xff)) << (8 * u);
  }
  wQ[(((size_t)(lane >> 2) * G3 + row) << 2) + (lane & 3)] = d;
}

// ---- generic per-row symmetric i8 quantizer: out[row][kd] dwords + scale ----
__global__ __launch_bounds__(256)
void quant_rows(const float* __restrict__ A, const int* __restrict__ rowidx,
                uint32_t* __restrict__ out, float* __restrict__ scale,
                int M, int K, int Kd) {
  const int row = blockIdx.x * 4 + (threadIdx.x >> 6);
  const int lane = threadIdx.x & 63;
  if (row >= M) return;
  const float* ar = A + (long)(rowidx ? rowidx[row] : row) * K;
  float m = 0.0f;
  for (int e = lane; e < K; e += 64) m = fmaxf(m, fabsf(ar[e]));
  for (int off = 32; off > 0; off >>= 1) m = fmaxf(m, __shfl_xor(m, off, 64));
  const float inv = m > 0.0f ? 127.0f / m : 0.0f;
  if (lane == 0) scale[row] = m * (1.0f / 127.0f);
  for (int kd = lane; kd < Kd; kd += 64) {
    uint32_t d = 0;
#pragma unroll
    for (int u = 0; u < 4; ++u) {
      const int e = 4 * kd + u;
      int qv = (e < K) ? __float2int_rn(ar[e] * inv) : 0;
      qv = qv > 127 ? 127 : (qv < -127 ? -127 : qv);
      d |= ((uint32_t)(qv & 0xff)) << (8 * u);
    }
    out[(long)row * Kd + kd] = d;
  }
}

// ---- bsum = bih + bhh for gates r,z; bih only for gate n ----
__global__ void bias_combine(const float* __restrict__ bih, const float* __restrict__ bhh,
                             float* __restrict__ bsum) {
  const int i = blockIdx.x * 256 + threadIdx.x;   // 0..767
  float v = bih[i];
  if (i < 2 * H_) v += bhh[i];
  bsum[i] = v;
}

// ---- dtok[i] = Xin[b*L + Xindex[i]] ----
__global__ void gather_dtok(const int* __restrict__ Xin, const int* __restrict__ Xindex,
                            int* __restrict__ dtok) {
  const int i = blockIdx.x * 256 + threadIdx.x;   // 0..1023
  const int b = i >> 5;                           // /T_
  dtok[i] = Xin[b * L_ + Xindex[i]];
}

// ---- i8 GEMM: C[M,N] = (Aq . Wq^T) * sa[m] * sw[n] (+bias[n]) ----
template<bool TRANSP, bool BIAS>
__global__ __launch_bounds__(256)
void gemm_i8(const uint32_t* __restrict__ Aq, const float* __restrict__ sa,
             const uint32_t* __restrict__ Wq, const float* __restrict__ swc,
             const float* __restrict__ bias, float* __restrict__ C,
             int M, int N, int Kd) {
  __shared__ uint32_t As[8][68];
  __shared__ uint32_t Ws[8][68];
  const int tid = threadIdx.x;
  const int bm = blockIdx.x, bn = blockIdx.y;
  const int ty = tid >> 4, tx = tid & 15;
  const int srow = tid >> 2;
  const int skd = (tid & 3) << 1;
  const uint32_t* Arow = Aq + (long)(bm * 64 + srow) * Kd + skd;
  const uint32_t* Wrow = Wq + (long)(bn * 64 + srow) * Kd + skd;
  int acc[4][4] = {};
  for (int k0 = 0; k0 < Kd; k0 += 8) {
    const uint32_t a0 = Arow[k0], a1 = Arow[k0 + 1];
    const uint32_t w0 = Wrow[k0], w1 = Wrow[k0 + 1];
    __syncthreads();
    As[skd][srow] = a0; As[skd + 1][srow] = a1;
    Ws[skd][srow] = w0; Ws[skd + 1][srow] = w1;
    __syncthreads();
#pragma unroll
    for (int kd = 0; kd < 8; ++kd) {
      const uint4 a4 = *(const uint4*)&As[kd][ty << 2];
      const uint4 b4 = *(const uint4*)&Ws[kd][tx << 2];
      acc[0][0] = sdot4(a4.x, b4.x, acc[0][0]);
      acc[0][1] = sdot4(a4.x, b4.y, acc[0][1]);
      acc[0][2] = sdot4(a4.x, b4.z, acc[0][2]);
      acc[0][3] = sdot4(a4.x, b4.w, acc[0][3]);
      acc[1][0] = sdot4(a4.y, b4.x, acc[1][0]);
      acc[1][1] = sdot4(a4.y, b4.y, acc[1][1]);
      acc[1][2] = sdot4(a4.y, b4.z, acc[1][2]);
      acc[1][3] = sdot4(a4.y, b4.w, acc[1][3]);
      acc[2][0] = sdot4(a4.z, b4.x, acc[2][0]);
      acc[2][1] = sdot4(a4.z, b4.y, acc[2][1]);
      acc[2][2] = sdot4(a4.z, b4.z, acc[2][2]);
      acc[2][3] = sdot4(a4.z, b4.w, acc[2][3]);
      acc[3][0] = sdot4(a4.w, b4.x, acc[3][0]);
      acc[3][1] = sdot4(a4.w, b4.y, acc[3][1]);
      acc[3][2] = sdot4(a4.w, b4.z, acc[3][2]);
      acc[3][3] = sdot4(a4.w, b4.w, acc[3][3]);
    }
  }
#pragma unroll
  for (int i = 0; i < 4; ++i) {
    const int m = bm * 64 + (ty << 2) + i;
    const float sai = sa[m];
#pragma unroll
    for (int j = 0; j < 4; ++j) {
      const int n = bn * 64 + (tx << 2) + j;
      float v = (float)acc[i][j] * sai * swc[n];
      if (BIAS) v += bias[n];
      if (TRANSP) C[(((long)(m >> 8) * N + n) << 8) + (m & 255)] = v;
      else        C[(long)m * N + n] = v;
    }
  }
}

// ==== sequential GRU, 1024 thr, 4-way K-split, weights = 6 reg + 6 L2 ====
// tid = q*256+j; thread owns rows {j,H+j,2H+j}, chunks c = q*4+u (u=0..3),
// chunk = uint4 of K-dwords 4c..4c+3 at wQv[c*768+row] (coalesced dwordx4).
// u=2,3 pinned in registers (24 VGPR, proven resident r13); u=0,1 streamed
// from L2 each step (98 KB/CU-step / ~119 B/cy ~= 825 cy) while the LDS pipe
// carries only h-broadcasts (~770 cy) -- ports run in parallel (r13: putting
// weights in LDS serialized 160 b128 ops on the one LDS pipe = 1990 cy/step).

#define PIN4(v) asm volatile("" : "+v"(v.x), "+v"(v.y), "+v"(v.z), "+v"(v.w))
#define DOT4W(accv, wv, hp) { \
  accv = sdot4(wv.x, hp.x, accv); accv = sdot4(wv.y, hp.y, accv); \
  accv = sdot4(wv.z, hp.z, accv); accv = sdot4(wv.w, hp.w, accv); }

__global__ __launch_bounds__(1024)
void gru_seq(const float* __restrict__ xg, const uint4* __restrict__ wQv,
             const float* __restrict__ sw, const float* __restrict__ bhh,
             const float* __restrict__ h0, float* __restrict__ hout,
             float* __restrict__ hlast, int S) {
  const int b = blockIdx.x;
  const int tid = threadIdx.x;
  const int j = tid & 255;
  const int q = tid >> 8;
  const int c0 = q * 4;
  // streamed chunk offsets (uint4 index)
  const int o_r0 = (c0 + 0) * G3 + j,        o_r1 = (c0 + 1) * G3 + j;
  const int o_z0 = o_r0 + H_,                o_z1 = o_r1 + H_;
  const int o_n0 = o_r0 + 2 * H_,            o_n1 = o_r1 + 2 * H_;
  // register-resident chunks u=2,3
  uint4 wr2 = wQv[(c0 + 2) * G3 + j],          wr3 = wQv[(c0 + 3) * G3 + j];
  uint4 wz2 = wQv[(c0 + 2) * G3 + H_ + j],     wz3 = wQv[(c0 + 3) * G3 + H_ + j];
  uint4 wn2 = wQv[(c0 + 2) * G3 + 2 * H_ + j], wn3 = wQv[(c0 + 3) * G3 + 2 * H_ + j];
  PIN4(wr2); PIN4(wr3); PIN4(wz2); PIN4(wz3); PIN4(wn2); PIN4(wn3);
  __shared__ __align__(16) uint32_t h2[2][H_ / 4];   // i8 h, double-buffered
  __shared__ int part[3][4][H_];                     // [gate][q][j]; q=0 unused
  float bhn = 0.0f, h = 0.0f, swr = 0.0f, swz = 0.0f, swn = 0.0f;
  const float* xp = xg + (long)b * S * G3;
  float* hp_out = hout + (long)b * S * H_;
  if (q == 0) {
    bhn = bhh[2 * H_ + j];
    swr = sw[j]; swz = sw[H_ + j]; swn = sw[2 * H_ + j];
    h = h0 ? h0[b * H_ + j] : 0.0f;
    ((signed char*)h2[0])[j] = (signed char)__float2int_rn(h * 127.0f);
  }
  __syncthreads();
  for (int t = 0; t < S; ++t) {
    const uint4* hq = (const uint4*)h2[t & 1] + q * 4;
    int ar = 0, az = 0, an = 0;
    // r-gate: issue stream, cover with reg-chunk dots
    uint4 s0 = wQv[o_r0], s1 = wQv[o_r1];
    float xr = 0.0f, xz = 0.0f, xn = 0.0f;
    if (q == 0) { xr = xp[j]; xz = xp[H_ + j]; xn = xp[2 * H_ + j]; }
    const uint4 hp2 = hq[2], hp3 = hq[3];
    DOT4W(ar, wr2, hp2) DOT4W(ar, wr3, hp3)
    const uint4 hp0 = hq[0], hp1 = hq[1];
    DOT4W(ar, s0, hp0) DOT4W(ar, s1, hp1)
    __builtin_amdgcn_sched_barrier(0);
    // z-gate
    s0 = wQv[o_z0]; s1 = wQv[o_z1];
    DOT4W(az, wz2, hp2) DOT4W(az, wz3, hp3)
    DOT4W(az, s0, hp0) DOT4W(az, s1, hp1)
    __builtin_amdgcn_sched_barrier(0);
    // n-gate
    s0 = wQv[o_n0]; s1 = wQv[o_n1];
    DOT4W(an, wn2, hp2) DOT4W(an, wn3, hp3)
    DOT4W(an, s0, hp0) DOT4W(an, s1, hp1)
    if (q) { part[0][q][j] = ar; part[1][q][j] = az; part[2][q][j] = an; }
    __syncthreads();
    if (q == 0) {
      const float arf = (float)(ar + part[0][1][j] + part[0][2][j] + part[0][3][j]) * swr;
      const float azf = (float)(az + part[1][1][j] + part[1][2][j] + part[1][3][j]) * swz;
      const float anf = (float)(an + part[2][1][j] + part[2][2][j] + part[2][3][j]) * swn;
      const float r = sigmoid_f(xr + arf);           // xr has bih_r + bhh_r
      const float z = sigmoid_f(xz + azf);           // xz has bih_z + bhh_z
      const float n = tanh_f(xn + r * (anf + bhn));
      h = (1.0f - z) * n + z * h;
      hp_out[j] = h;
      ((signed char*)h2[(t & 1) ^ 1])[j] = (signed char)__float2int_rn(h * 127.0f);
    }
    xp += G3;
    hp_out += H_;
    __syncthreads();
  }
  if (q == 0 && hlast) hlast[b * H_ + j] = h;
}

// ---- fused pointer layer + masked log-softmax + loss accumulation ----
__global__ __launch_bounds__(256)
void pointer_loss(const float* __restrict__ WEt, const float* __restrict__ WD,
                  const float* __restrict__ Vv,
                  const int* __restrict__ Xindex, const int* __restrict__ Yindex,
                  const int* __restrict__ lens, float* __restrict__ out) {
  const int t = blockIdx.x, b = blockIdx.y;
  const int l = threadIdx.x;
  __shared__ float wd_s[H_], vv_s[H_];
  __shared__ float rbuf[4], sbuf[4], vy_s;
  const int bt = b * T_ + t;
  wd_s[l] = WD[(long)bt * H_ + l];
  vv_s[l] = Vv[l] * 1.0507009873554805f;
  __syncthreads();
  const float* wet = WEt + (long)b * H_ * L_;
  const float alpha = 1.6732632423543772f;
  float acc = 0.0f;
#pragma unroll 4
  for (int hh = 0; hh < H_; ++hh) {
    const float xsum = wet[hh * L_ + l] + wd_s[hh];
    const float sneg = alpha * (__expf(xsum) - 1.0f);
    const float s = xsum > 0.0f ? xsum : sneg;
    acc = fmaf(s, vv_s[hh], acc);
  }
  float v;
  {
    const float sneg = alpha * (__expf(acc) - 1.0f);
    v = 1.0507009873554805f * (acc > 0.0f ? acc : sneg);
  }
  const int start = Xindex[bt];
  const int len = lens[b];
  const bool valid = (l >= start) && (l < len);
  const int y = Yindex[bt];
  if (l == y) vy_s = v;
  float m = valid ? v : -INFINITY;
  for (int off = 32; off > 0; off >>= 1) m = fmaxf(m, __shfl_xor(m, off, 64));
  const int wid = l >> 6, lane = l & 63;
  if (lane == 0) rbuf[wid] = m;
  __syncthreads();
  const float mx = fmaxf(fmaxf(rbuf[0], rbuf[1]), fmaxf(rbuf[2], rbuf[3]));
  float e = valid ? __expf(v - mx) : 0.0f;
  for (int off = 32; off > 0; off >>= 1) e += __shfl_xor(e, off, 64);
  if (lane == 0) sbuf[wid] = e;
  __syncthreads();
  if (l == 0) {
    const float sum = sbuf[0] + sbuf[1] + sbuf[2] + sbuf[3];
    atomicAdd(out, (mx + __logf(sum) - vy_s) * (1.0f / (B_ * T_)));
  }
}

extern "C" void kernel_launch(void* const* d_in, const int* in_sizes, int n_in,
                              void* d_out, int out_size, void* d_ws, size_t ws_size,
                              hipStream_t stream) {
  (void)in_sizes; (void)n_in; (void)out_size; (void)ws_size;
  const int*   Xin    = (const int*)d_in[0];
  const int*   Xindex = (const int*)d_in[1];
  const int*   Yindex = (const int*)d_in[2];
  const int*   lens   = (const int*)d_in[3];
  const float* emb    = (const float*)d_in[4];
  const float* Wih_e  = (const float*)d_in[5];
  const float* Whh_e  = (const float*)d_in[6];
  const float* bih_e  = (const float*)d_in[7];
  const float* bhh_e  = (const float*)d_in[8];
  const float* Wih_d  = (const float*)d_in[9];
  const float* Whh_d  = (const float*)d_in[10];
  const float* bih_d  = (const float*)d_in[11];
  const float* bhh_d  = (const float*)d_in[12];
  const float* W1     = (const float*)d_in[13];
  const float* W2     = (const float*)d_in[14];
  const float* Vv     = (const float*)d_in[15];

  char* p = (char*)d_ws;
  auto take = [&](size_t bytes) { void* q = (void*)p; p += (bytes + 255) & ~(size_t)255; return q; };
  uint32_t* wQ_e   = (uint32_t*)take((size_t)64 * G3 * 4);
  uint32_t* wQ_d   = (uint32_t*)take((size_t)64 * G3 * 4);
  float*    sw_e   = (float*)take((size_t)768 * 4);
  float*    sw_d   = (float*)take((size_t)768 * 4);
  uint32_t* WihQ_e = (uint32_t*)take((size_t)768 * 80 * 4);
  uint32_t* WihQ_d = (uint32_t*)take((size_t)768 * 80 * 4);
  float*    sWih_e = (float*)take((size_t)768 * 4);
  float*    sWih_d = (float*)take((size_t)768 * 4);
  uint32_t* W1q    = (uint32_t*)take((size_t)256 * 64 * 4);
  uint32_t* W2q    = (uint32_t*)take((size_t)256 * 64 * 4);
  float*    sW1    = (float*)take((size_t)256 * 4);
  float*    sW2    = (float*)take((size_t)256 * 4);
  float*    bsum_e = (float*)take((size_t)768 * 4);
  float*    bsum_d = (float*)take((size_t)768 * 4);
  int*      dtok   = (int*)take((size_t)1024 * 4);
  float*    xg_e   = (float*)take((size_t)8192 * 768 * 4);   // reused as WEt later
  float*    xg_d   = (float*)take((size_t)1024 * 768 * 4);
  float*    hn     = (float*)take((size_t)8192 * 256 * 4);
  float*    hend   = (float*)take((size_t)8192 * 4);
  float*    hl_d   = (float*)take((size_t)8192 * 4);
  float*    doutb  = (float*)take((size_t)1024 * 256 * 4);
  float*    WDb    = (float*)take((size_t)1024 * 256 * 4);
  uint32_t* Aqe    = (uint32_t*)take((size_t)8192 * 80 * 4); // reused as hnq later
  float*    saAe   = (float*)take((size_t)8192 * 4);         // reused as sahn
  uint32_t* Aqd    = (uint32_t*)take((size_t)1024 * 80 * 4); // reused as dq
  float*    saAd   = (float*)take((size_t)1024 * 4);         // reused as sad
  float*    WEt  = xg_e;            // xg_e dead after encoder GRU
  uint32_t* hnq  = Aqe;             // Aqe dead after xg GEMMs
  float*    sahn = saAe;
  uint32_t* dq   = Aqd;
  float*    sad  = saAd;

  hipMemsetAsync(d_out, 0, sizeof(float), stream);

  hipLaunchKernelGGL(pack_whh_i8, dim3(192), dim3(256), 0, stream, Whh_e, wQ_e, sw_e);
  hipLaunchKernelGGL(pack_whh_i8, dim3(192), dim3(256), 0, stream, Whh_d, wQ_d, sw_d);
  hipLaunchKernelGGL(bias_combine, dim3(3), dim3(256), 0, stream, bih_e, bhh_e, bsum_e);
  hipLaunchKernelGGL(bias_combine, dim3(3), dim3(256), 0, stream, bih_d, bhh_d, bsum_d);
  hipLaunchKernelGGL(gather_dtok, dim3(4), dim3(256), 0, stream, Xin, Xindex, dtok);

  // quantize weights: Wih K=300->Kd=80, W1/W2 K=256->Kd=64
  hipLaunchKernelGGL(quant_rows, dim3(192), dim3(256), 0, stream,
                     Wih_e, (const int*)nullptr, WihQ_e, sWih_e, 768, 300, 80);
  hipLaunchKernelGGL(quant_rows, dim3(192), dim3(256), 0, stream,
                     Wih_d, (const int*)nullptr, WihQ_d, sWih_d, 768, 300, 80);
  hipLaunchKernelGGL(quant_rows, dim3(64), dim3(256), 0, stream,
                     W1, (const int*)nullptr, W1q, sW1, 256, 256, 64);
  hipLaunchKernelGGL(quant_rows, dim3(64), dim3(256), 0, stream,
                     W2, (const int*)nullptr, W2q, sW2, 256, 256, 64);
  // quantize gathered embedding rows
  hipLaunchKernelGGL(quant_rows, dim3(2048), dim3(256), 0, stream,
                     emb, Xin, Aqe, saAe, 8192, 300, 80);
  hipLaunchKernelGGL(quant_rows, dim3(256), dim3(256), 0, stream,
                     emb, dtok, Aqd, saAd, 1024, 300, 80);

  // xg = Aq @ WihQ^T scaled + bsum
  hipLaunchKernelGGL((gemm_i8<false, true>), dim3(128, 12), dim3(256), 0, stream,
                     Aqe, saAe, WihQ_e, sWih_e, bsum_e, xg_e, 8192, 768, 80);
  hipLaunchKernelGGL((gemm_i8<false, true>), dim3(16, 12), dim3(256), 0, stream,
                     Aqd, saAd, WihQ_d, sWih_d, bsum_d, xg_d, 1024, 768, 80);

  // encoder GRU (h0 = 0) -> hn, hend; decoder GRU (h0 = hend) -> doutb
  hipLaunchKernelGGL(gru_seq, dim3(32), dim3(1024), 0, stream,
                     xg_e, (const uint4*)wQ_e, sw_e, bhh_e, (const float*)nullptr,
                     hn, hend, L_);
  hipLaunchKernelGGL(gru_seq, dim3(32), dim3(1024), 0, stream,
                     xg_d, (const uint4*)wQ_d, sw_d, bhh_d, hend, doutb, hl_d, T_);

  // quantize GRU outputs, then pointer GEMMs
  hipLaunchKernelGGL(quant_rows, dim3(2048), dim3(256), 0, stream,
                     hn, (const int*)nullptr, hnq, sahn, 8192, 256, 64);
  hipLaunchKernelGGL(quant_rows, dim3(256), dim3(256), 0, stream,
                     doutb, (const int*)nullptr, dq, sad, 1024, 256, 64);
  // WEt[b][k][l] (transposed store), WD[b,t,k]
  hipLaunchKernelGGL((gemm_i8<true, false>), dim3(128, 4), dim3(256), 0, stream,
                     hnq, sahn, W1q, sW1, (const float*)nullptr, WEt, 8192, 256, 64);
  hipLaunchKernelGGL((gemm_i8<false, false>), dim3(16, 4), dim3(256), 0, stream,
                     dq, sad, W2q, sW2, (const float*)nullptr, WDb, 1024, 256, 64);

  // fused pointer layer + loss
  hipLaunchKernelGGL(pointer_loss, dim3(T_, B_), dim3(256), 0, stream,
                     WEt, WDb, Vv, Xindex, Yindex, lens, (float*)d_out);
}